// Round 7
// baseline (468.947 us; speedup 1.0000x reference)
//
#include <hip/hip_runtime.h>
#include <hip/hip_bf16.h>

#define FIN 128
#define FOUT 64
#define TILE_ROWS 64
#define SX_STRIDE 132      // 128 + 4 pad

#define EPB 4096           // edges per sort block
#define NPB 64             // nodes per coarse bucket (d >> 6)
#define NBUK_MAX 1024

// Workspace layout (bytes, 16B-aligned):
//   [0, 6,400,000)           support   : N*64 bf16
//   [6,400,000, +613,088)    hist      : NBUK*SB int (bucket-major [b][B])
//   [7,013,088, +1,024)      blocksums : 256 int
//   [7,014,112, +6,400,000)  tmp       : E int2 {src | dloc<<16, ev}
#define OFF_HIST      6400000
#define OFF_BLOCKSUMS 7013088
#define OFF_TMP       7014112

#define SCAN_CHUNK 1024

// f32 -> bf16 round-to-nearest-even (bit-level)
__device__ inline ushort f32_to_bf16_rne(float f) {
    unsigned u = __float_as_uint(f);
    u += 0x7FFFu + ((u >> 16) & 1u);
    return (ushort)(u >> 16);
}
__device__ inline float bf16_to_f32(ushort h) {
    return __uint_as_float((unsigned)h << 16);
}

// ---------------------------------------------------------------------------
// Fused: blocks [0,GB) -> support(bf16) = (x@W)*t[:,None]; blocks [GB,..)
// -> coarse dst histogram. LDS = 34+4 KB -> 4 blocks/CU (R4's 66 KB mistake
// avoided). W reads hit L1; only X tile LDS-staged.
// ---------------------------------------------------------------------------
__global__ __launch_bounds__(256) void gemm_hist_kernel(
    const float* __restrict__ x, const float* __restrict__ t,
    const float* __restrict__ W, ushort* __restrict__ support, int N,
    const int* __restrict__ dst, int* __restrict__ hist,
    int E, int SB, int NBUK, int GB)
{
    __shared__ float sX[TILE_ROWS * SX_STRIDE];
    __shared__ int   h[NBUK_MAX];

    const int tid = threadIdx.x;

    if (blockIdx.x >= GB) {
        // ---- histogram branch ----
        const int hb = blockIdx.x - GB;
        for (int i = tid; i < NBUK; i += 256) h[i] = 0;
        __syncthreads();
        const int e0 = hb * EPB;
        for (int i = tid; i < EPB; i += 256) {
            int e = e0 + i;
            if (e < E) atomicAdd(&h[dst[e] >> 6], 1);
        }
        __syncthreads();
        for (int i = tid; i < NBUK; i += 256)
            hist[i * SB + hb] = h[i];
        return;
    }

    // ---- GEMM branch ----
    const int row0 = blockIdx.x * TILE_ROWS;

    #pragma unroll
    for (int i = 0; i < 8; ++i) {
        int idx = (i * 256 + tid) * 4;
        int r   = idx >> 7;
        int c   = idx & 127;
        float4 v = make_float4(0.f, 0.f, 0.f, 0.f);
        if (row0 + r < N)
            v = *(const float4*)&x[(size_t)(row0 + r) * FIN + c];
        *(float4*)&sX[r * SX_STRIDE + c] = v;
    }
    __syncthreads();

    const int tx = tid & 15;
    const int ty = tid >> 4;

    float acc[4][4];
    #pragma unroll
    for (int i = 0; i < 4; ++i)
        #pragma unroll
        for (int j = 0; j < 4; ++j)
            acc[i][j] = 0.f;

    #pragma unroll 8
    for (int k = 0; k < FIN; ++k) {
        float4 w = *(const float4*)&W[k * FOUT + tx * 4];   // L1-resident
        float xs[4];
        #pragma unroll
        for (int i = 0; i < 4; ++i)
            xs[i] = sX[(ty * 4 + i) * SX_STRIDE + k];
        #pragma unroll
        for (int i = 0; i < 4; ++i) {
            acc[i][0] += xs[i] * w.x;
            acc[i][1] += xs[i] * w.y;
            acc[i][2] += xs[i] * w.z;
            acc[i][3] += xs[i] * w.w;
        }
    }

    #pragma unroll
    for (int i = 0; i < 4; ++i) {
        int r = row0 + ty * 4 + i;
        if (r < N) {
            float tv = t[r];
            ushort4 o;
            o.x = f32_to_bf16_rne(acc[i][0] * tv);
            o.y = f32_to_bf16_rne(acc[i][1] * tv);
            o.z = f32_to_bf16_rne(acc[i][2] * tv);
            o.w = f32_to_bf16_rne(acc[i][3] * tv);
            *(ushort4*)&support[(size_t)r * FOUT + tx * 4] = o;
        }
    }
}

// ---------------------------------------------------------------------------
// scan stage 1: per-block sums of SCAN_CHUNK elements
// ---------------------------------------------------------------------------
__global__ __launch_bounds__(256) void scan_sums_kernel(
    const int* __restrict__ counts, int* __restrict__ blocksums, int M)
{
    __shared__ int red[256];
    const int tid  = threadIdx.x;
    const int base = blockIdx.x * SCAN_CHUNK + tid * 4;

    int s = 0;
    if (base + 3 < M) {
        int4 c = *(const int4*)&counts[base];
        s = c.x + c.y + c.z + c.w;
    } else {
        for (int i = 0; i < 4; ++i)
            if (base + i < M) s += counts[base + i];
    }
    red[tid] = s;
    __syncthreads();
    #pragma unroll
    for (int d = 128; d > 0; d >>= 1) {
        if (tid < d) red[tid] += red[tid + d];
        __syncthreads();
    }
    if (tid == 0) blocksums[blockIdx.x] = red[0];
}

// ---------------------------------------------------------------------------
// scan stage 2: one block scans <=256 block sums -> exclusive
// ---------------------------------------------------------------------------
__global__ __launch_bounds__(256) void scan_block_kernel(
    int* __restrict__ blocksums, int NB)
{
    __shared__ int s[256];
    const int tid = threadIdx.x;
    int v = (tid < NB) ? blocksums[tid] : 0;
    s[tid] = v;
    __syncthreads();
    #pragma unroll
    for (int d = 1; d < 256; d <<= 1) {
        int add = (tid >= d) ? s[tid - d] : 0;
        __syncthreads();
        s[tid] += add;
        __syncthreads();
    }
    if (tid < NB) blocksums[tid] = s[tid] - v;
}

// ---------------------------------------------------------------------------
// scan stage 3: counts[j] <- exclusive prefix, in place
// ---------------------------------------------------------------------------
__global__ __launch_bounds__(256) void scan_apply_excl_kernel(
    int* __restrict__ counts, const int* __restrict__ blocksums, int M)
{
    __shared__ int s[256];
    const int tid  = threadIdx.x;
    const int base = blockIdx.x * SCAN_CHUNK + tid * 4;

    int c[4] = {0, 0, 0, 0};
    if (base + 3 < M) {
        int4 cc = *(const int4*)&counts[base];
        c[0] = cc.x; c[1] = cc.y; c[2] = cc.z; c[3] = cc.w;
    } else {
        for (int i = 0; i < 4; ++i)
            if (base + i < M) c[i] = counts[base + i];
    }
    int mysum = c[0] + c[1] + c[2] + c[3];
    s[tid] = mysum;
    __syncthreads();
    #pragma unroll
    for (int d = 1; d < 256; d <<= 1) {
        int add = (tid >= d) ? s[tid - d] : 0;
        __syncthreads();
        s[tid] += add;
        __syncthreads();
    }
    int ex = blocksums[blockIdx.x] + s[tid] - mysum;
    #pragma unroll
    for (int i = 0; i < 4; ++i) {
        if (base + i < M) {
            counts[base + i] = ex;
            ex += c[i];
        }
    }
}

// ---------------------------------------------------------------------------
// coarse scatter: private per-(block,bucket) cursors (LDS atomics only).
// rec = {src | (d&63)<<16, ev_bits}   (src < 65536 required: N = 50000 ok)
// ---------------------------------------------------------------------------
__global__ __launch_bounds__(256) void coarse_scatter_kernel(
    const int* __restrict__ src, const int* __restrict__ dst,
    const float* __restrict__ ev, const int* __restrict__ scanned,
    int2* __restrict__ tmp, int E, int SB, int NBUK)
{
    __shared__ int cur[NBUK_MAX];
    const int tid = threadIdx.x;
    for (int i = tid; i < NBUK; i += 256)
        cur[i] = scanned[i * SB + blockIdx.x];
    __syncthreads();

    const int e0 = blockIdx.x * EPB;
    for (int i = tid; i < EPB; i += 256) {
        int e = e0 + i;
        if (e < E) {
            int d   = dst[e];
            int pos = atomicAdd(&cur[d >> 6], 1);
            tmp[pos] = make_int2(src[e] | ((d & (NPB - 1)) << 16),
                                 __float_as_int(ev[e]));
        }
    }
}

// ---------------------------------------------------------------------------
// bucket_accum: one block per coarse bucket (64 nodes). Streams the bucket's
// tmp records once; lanes atomicAdd into a 64x64 f32 LDS accumulator
// (2-way bank alias = free); writes out rows once, coalesced, +bias.
// Replaces fine_sort + gather: no pairs/off arrays, no global atomics.
// ---------------------------------------------------------------------------
__global__ __launch_bounds__(256) void bucket_accum_kernel(
    const int* __restrict__ scanned, const int2* __restrict__ tmp,
    const ushort* __restrict__ support, const float* __restrict__ bias,
    float* __restrict__ out, int E, int N, int SB, int NBUK)
{
    __shared__ float acc[NPB * FOUT];   // 16 KB

    const int tid  = threadIdx.x;
    const int w    = tid >> 6;          // wave 0..3
    const int lane = tid & 63;
    const int B    = blockIdx.x;

    #pragma unroll
    for (int i = 0; i < 4; ++i)
        *(float4*)&acc[(i * 256 + tid) * 4] = make_float4(0.f, 0.f, 0.f, 0.f);
    __syncthreads();

    const int base = scanned[B * SB];
    const int endB = (B + 1 < NBUK) ? scanned[(B + 1) * SB] : E;

    // 4 waves stride the bucket's records; 4x manual unroll for MLP depth.
    int i = base + w;
    for (; i + 12 < endB; i += 16) {
        int2 r0 = tmp[i];
        int2 r1 = tmp[i + 4];
        int2 r2 = tmp[i + 8];
        int2 r3 = tmp[i + 12];
        float v0 = bf16_to_f32(support[(size_t)(r0.x & 0xFFFF) * FOUT + lane]);
        float v1 = bf16_to_f32(support[(size_t)(r1.x & 0xFFFF) * FOUT + lane]);
        float v2 = bf16_to_f32(support[(size_t)(r2.x & 0xFFFF) * FOUT + lane]);
        float v3 = bf16_to_f32(support[(size_t)(r3.x & 0xFFFF) * FOUT + lane]);
        atomicAdd(&acc[((r0.x >> 16) & 63) * FOUT + lane], v0 * __int_as_float(r0.y));
        atomicAdd(&acc[((r1.x >> 16) & 63) * FOUT + lane], v1 * __int_as_float(r1.y));
        atomicAdd(&acc[((r2.x >> 16) & 63) * FOUT + lane], v2 * __int_as_float(r2.y));
        atomicAdd(&acc[((r3.x >> 16) & 63) * FOUT + lane], v3 * __int_as_float(r3.y));
    }
    for (; i < endB; i += 4) {
        int2 r = tmp[i];
        float v = bf16_to_f32(support[(size_t)(r.x & 0xFFFF) * FOUT + lane]);
        atomicAdd(&acc[((r.x >> 16) & 63) * FOUT + lane], v * __int_as_float(r.y));
    }
    __syncthreads();

    const float bv = bias[lane];
    const int node0 = B * NPB;
    for (int n = w; n < NPB; n += 4) {
        int node = node0 + n;
        if (node < N)
            out[(size_t)node * FOUT + lane] = acc[n * FOUT + lane] + bv;
    }
}

extern "C" void kernel_launch(void* const* d_in, const int* in_sizes, int n_in,
                              void* d_out, int out_size, void* d_ws, size_t ws_size,
                              hipStream_t stream) {
    const float* x    = (const float*)d_in[0];
    const float* t    = (const float*)d_in[1];
    const int*   src  = (const int*)d_in[2];
    const int*   dst  = (const int*)d_in[3];
    const float* ev   = (const float*)d_in[4];
    const float* W    = (const float*)d_in[5];
    const float* bias = (const float*)d_in[6];
    float* out = (float*)d_out;

    const int N = in_sizes[1];   // 50000
    const int E = in_sizes[2];   // 800000

    char*   ws        = (char*)d_ws;
    ushort* support   = (ushort*)ws;
    int*    hist      = (int*)(ws + OFF_HIST);
    int*    blocksums = (int*)(ws + OFF_BLOCKSUMS);
    int2*   tmp       = (int2*)(ws + OFF_TMP);

    const int GB   = (N + TILE_ROWS - 1) / TILE_ROWS;    // 782 gemm blocks
    const int SB   = (E + EPB - 1) / EPB;                // 196 sort blocks
    const int NBUK = (N + NPB - 1) / NPB;                // 782 coarse buckets
    const int M    = NBUK * SB;                          // 153,272
    const int NBS  = (M + SCAN_CHUNK - 1) / SCAN_CHUNK;  // 150 (<=256)

    // 1) fused: support = bf16((x@W)*t) + coarse histogram
    gemm_hist_kernel<<<GB + SB, 256, 0, stream>>>(
        x, t, W, support, N, dst, hist, E, SB, NBUK, GB);

    // 2) exclusive scan of hist matrix
    scan_sums_kernel<<<NBS, 256, 0, stream>>>(hist, blocksums, M);
    scan_block_kernel<<<1, 256, 0, stream>>>(blocksums, NBS);
    scan_apply_excl_kernel<<<NBS, 256, 0, stream>>>(hist, blocksums, M);

    // 3) coarse scatter into bucket-ordered tmp
    coarse_scatter_kernel<<<SB, 256, 0, stream>>>(
        src, dst, ev, hist, tmp, E, SB, NBUK);

    // 4) per-bucket LDS accumulation -> out (+bias)
    bucket_accum_kernel<<<NBUK, 256, 0, stream>>>(
        hist, tmp, support, bias, out, E, N, SB, NBUK);
}

// Round 8
// 170.814 us; speedup vs baseline: 2.7454x; 2.7454x over previous
//
#include <hip/hip_runtime.h>
#include <hip/hip_bf16.h>

#define FIN 128
#define FOUT 64
#define TILE_ROWS 64
#define SX_STRIDE 132      // 128 + 4 pad

#define EPB 4096           // edges per sort block
#define NPB 64             // nodes per coarse bucket (d >> 6)
#define NBUK_MAX 1024
#define CAP 1536           // records per bucket cap (mean 1024, +16 sigma)

// Workspace layout (bytes, 16B-aligned):
//   [0, 6,400,000)           support   : N*64 bf16
//   [6,400,000, +613,088)    hist      : NBUK*SB int (bucket-major [b][B])
//   [7,013,088, +1,024)      blocksums : 256 int
//   [7,014,112, +6,400,000)  tmp       : E int2 {src | dloc<<16, ev}
#define OFF_HIST      6400000
#define OFF_BLOCKSUMS 7013088
#define OFF_TMP       7014112

#define SCAN_CHUNK 1024

// f32 -> bf16 round-to-nearest-even (bit-level)
__device__ inline ushort f32_to_bf16_rne(float f) {
    unsigned u = __float_as_uint(f);
    u += 0x7FFFu + ((u >> 16) & 1u);
    return (ushort)(u >> 16);
}
__device__ inline float bf16_to_f32(ushort h) {
    return __uint_as_float((unsigned)h << 16);
}

// ---------------------------------------------------------------------------
// Fused: blocks [0,GB) -> support(bf16) = (x@W)*t[:,None]; blocks [GB,..)
// -> coarse dst histogram. LDS 33.8+4 KB -> 4 blocks/CU.
// ---------------------------------------------------------------------------
__global__ __launch_bounds__(256) void gemm_hist_kernel(
    const float* __restrict__ x, const float* __restrict__ t,
    const float* __restrict__ W, ushort* __restrict__ support, int N,
    const int* __restrict__ dst, int* __restrict__ hist,
    int E, int SB, int NBUK, int GB)
{
    __shared__ float sX[TILE_ROWS * SX_STRIDE];
    __shared__ int   h[NBUK_MAX];

    const int tid = threadIdx.x;

    if (blockIdx.x >= GB) {
        // ---- histogram branch ----
        const int hb = blockIdx.x - GB;
        for (int i = tid; i < NBUK; i += 256) h[i] = 0;
        __syncthreads();
        const int e0 = hb * EPB;
        for (int i = tid; i < EPB; i += 256) {
            int e = e0 + i;
            if (e < E) atomicAdd(&h[dst[e] >> 6], 1);
        }
        __syncthreads();
        for (int i = tid; i < NBUK; i += 256)
            hist[i * SB + hb] = h[i];
        return;
    }

    // ---- GEMM branch ----
    const int row0 = blockIdx.x * TILE_ROWS;

    #pragma unroll
    for (int i = 0; i < 8; ++i) {
        int idx = (i * 256 + tid) * 4;
        int r   = idx >> 7;
        int c   = idx & 127;
        float4 v = make_float4(0.f, 0.f, 0.f, 0.f);
        if (row0 + r < N)
            v = *(const float4*)&x[(size_t)(row0 + r) * FIN + c];
        *(float4*)&sX[r * SX_STRIDE + c] = v;
    }
    __syncthreads();

    const int tx = tid & 15;
    const int ty = tid >> 4;

    float acc[4][4];
    #pragma unroll
    for (int i = 0; i < 4; ++i)
        #pragma unroll
        for (int j = 0; j < 4; ++j)
            acc[i][j] = 0.f;

    #pragma unroll 8
    for (int k = 0; k < FIN; ++k) {
        float4 w = *(const float4*)&W[k * FOUT + tx * 4];   // L1-resident
        float xs[4];
        #pragma unroll
        for (int i = 0; i < 4; ++i)
            xs[i] = sX[(ty * 4 + i) * SX_STRIDE + k];
        #pragma unroll
        for (int i = 0; i < 4; ++i) {
            acc[i][0] += xs[i] * w.x;
            acc[i][1] += xs[i] * w.y;
            acc[i][2] += xs[i] * w.z;
            acc[i][3] += xs[i] * w.w;
        }
    }

    #pragma unroll
    for (int i = 0; i < 4; ++i) {
        int r = row0 + ty * 4 + i;
        if (r < N) {
            float tv = t[r];
            ushort4 o;
            o.x = f32_to_bf16_rne(acc[i][0] * tv);
            o.y = f32_to_bf16_rne(acc[i][1] * tv);
            o.z = f32_to_bf16_rne(acc[i][2] * tv);
            o.w = f32_to_bf16_rne(acc[i][3] * tv);
            *(ushort4*)&support[(size_t)r * FOUT + tx * 4] = o;
        }
    }
}

// ---------------------------------------------------------------------------
// scan stage 1: per-block sums of SCAN_CHUNK elements
// ---------------------------------------------------------------------------
__global__ __launch_bounds__(256) void scan_sums_kernel(
    const int* __restrict__ counts, int* __restrict__ blocksums, int M)
{
    __shared__ int red[256];
    const int tid  = threadIdx.x;
    const int base = blockIdx.x * SCAN_CHUNK + tid * 4;

    int s = 0;
    if (base + 3 < M) {
        int4 c = *(const int4*)&counts[base];
        s = c.x + c.y + c.z + c.w;
    } else {
        for (int i = 0; i < 4; ++i)
            if (base + i < M) s += counts[base + i];
    }
    red[tid] = s;
    __syncthreads();
    #pragma unroll
    for (int d = 128; d > 0; d >>= 1) {
        if (tid < d) red[tid] += red[tid + d];
        __syncthreads();
    }
    if (tid == 0) blocksums[blockIdx.x] = red[0];
}

// ---------------------------------------------------------------------------
// scan stage 2: one block scans <=256 block sums -> exclusive
// ---------------------------------------------------------------------------
__global__ __launch_bounds__(256) void scan_block_kernel(
    int* __restrict__ blocksums, int NB)
{
    __shared__ int s[256];
    const int tid = threadIdx.x;
    int v = (tid < NB) ? blocksums[tid] : 0;
    s[tid] = v;
    __syncthreads();
    #pragma unroll
    for (int d = 1; d < 256; d <<= 1) {
        int add = (tid >= d) ? s[tid - d] : 0;
        __syncthreads();
        s[tid] += add;
        __syncthreads();
    }
    if (tid < NB) blocksums[tid] = s[tid] - v;
}

// ---------------------------------------------------------------------------
// scan stage 3: counts[j] <- exclusive prefix, in place
// ---------------------------------------------------------------------------
__global__ __launch_bounds__(256) void scan_apply_excl_kernel(
    int* __restrict__ counts, const int* __restrict__ blocksums, int M)
{
    __shared__ int s[256];
    const int tid  = threadIdx.x;
    const int base = blockIdx.x * SCAN_CHUNK + tid * 4;

    int c[4] = {0, 0, 0, 0};
    if (base + 3 < M) {
        int4 cc = *(const int4*)&counts[base];
        c[0] = cc.x; c[1] = cc.y; c[2] = cc.z; c[3] = cc.w;
    } else {
        for (int i = 0; i < 4; ++i)
            if (base + i < M) c[i] = counts[base + i];
    }
    int mysum = c[0] + c[1] + c[2] + c[3];
    s[tid] = mysum;
    __syncthreads();
    #pragma unroll
    for (int d = 1; d < 256; d <<= 1) {
        int add = (tid >= d) ? s[tid - d] : 0;
        __syncthreads();
        s[tid] += add;
        __syncthreads();
    }
    int ex = blocksums[blockIdx.x] + s[tid] - mysum;
    #pragma unroll
    for (int i = 0; i < 4; ++i) {
        if (base + i < M) {
            counts[base + i] = ex;
            ex += c[i];
        }
    }
}

// ---------------------------------------------------------------------------
// coarse scatter: private per-(block,bucket) cursors (LDS int atomics only).
// rec = {src | (d&63)<<16, ev_bits}   (src < 65536: N = 50000 ok)
// ---------------------------------------------------------------------------
__global__ __launch_bounds__(256) void coarse_scatter_kernel(
    const int* __restrict__ src, const int* __restrict__ dst,
    const float* __restrict__ ev, const int* __restrict__ scanned,
    int2* __restrict__ tmp, int E, int SB, int NBUK)
{
    __shared__ int cur[NBUK_MAX];
    const int tid = threadIdx.x;
    for (int i = tid; i < NBUK; i += 256)
        cur[i] = scanned[i * SB + blockIdx.x];
    __syncthreads();

    const int e0 = blockIdx.x * EPB;
    for (int i = tid; i < EPB; i += 256) {
        int e = e0 + i;
        if (e < E) {
            int d   = dst[e];
            int pos = atomicAdd(&cur[d >> 6], 1);
            tmp[pos] = make_int2(src[e] | ((d & (NPB - 1)) << 16),
                                 __float_as_int(ev[e]));
        }
    }
}

// ---------------------------------------------------------------------------
// bucket_gather: one block per 64-node bucket. LDS fine-sort (int atomics
// only) -> each wave walks its contiguous quarter of sorted records with a
// REGISTER accumulator + wave-uniform node-boundary flush. No float atomics.
// ---------------------------------------------------------------------------
__global__ __launch_bounds__(256) void bucket_gather_kernel(
    const int* __restrict__ scanned, const int2* __restrict__ tmp,
    const ushort* __restrict__ support, const float* __restrict__ bias,
    float* __restrict__ out, int E, int N, int SB, int NBUK)
{
    __shared__ int2 sorted[CAP];        // 12 KB
    __shared__ int  cnt[NPB];
    __shared__ int  incl[NPB];
    __shared__ int  starts[NPB + 1];
    __shared__ int  cur[NPB];

    const int tid  = threadIdx.x;
    const int w    = tid >> 6;
    const int lane = tid & 63;
    const int B    = blockIdx.x;
    const int node0 = B * NPB;

    const int base = scanned[B * SB];
    const int endB = (B + 1 < NBUK) ? scanned[(B + 1) * SB] : E;
    const int nrec = endB - base;
    const int placed = (nrec < CAP) ? nrec : CAP;

    if (tid < NPB) cnt[tid] = 0;
    __syncthreads();

    // count (first `placed` records)
    for (int i = tid; i < placed; i += 256)
        atomicAdd(&cnt[(tmp[base + i].x >> 16) & (NPB - 1)], 1);
    __syncthreads();

    // inclusive Hillis-Steele over 64 counters
    if (tid < NPB) incl[tid] = cnt[tid];
    __syncthreads();
    #pragma unroll
    for (int d = 1; d < NPB; d <<= 1) {
        int v = (tid < NPB && tid >= d) ? incl[tid - d] : 0;
        __syncthreads();
        if (tid < NPB) incl[tid] += v;
        __syncthreads();
    }
    if (tid < NPB) {
        int st = incl[tid] - cnt[tid];
        starts[tid] = st;
        cur[tid]    = st;
    }
    if (tid == 0) starts[NPB] = placed;
    __syncthreads();

    // reorder into sorted[] (tmp re-read hits L2)
    for (int i = tid; i < placed; i += 256) {
        int2 r  = tmp[base + i];
        int pos = atomicAdd(&cur[(r.x >> 16) & (NPB - 1)], 1);
        sorted[pos] = r;
    }
    __syncthreads();

    // walk: wave w owns nodes [w*16, (w+1)*16) == records [rbeg, rend)
    const float bv  = bias[lane];
    const int rbeg  = starts[w * 16];
    const int rend  = starts[w * 16 + 16];

    float accv = 0.f;
    int   curn = -1;

    int i = rbeg;
    while (i < rend) {
        if (i + 4 <= rend) {
            int2 a = sorted[i], b = sorted[i + 1], c = sorted[i + 2], d = sorted[i + 3];
            float va = bf16_to_f32(support[(size_t)(a.x & 0xFFFF) * FOUT + lane]);
            float vb = bf16_to_f32(support[(size_t)(b.x & 0xFFFF) * FOUT + lane]);
            float vc = bf16_to_f32(support[(size_t)(c.x & 0xFFFF) * FOUT + lane]);
            float vd = bf16_to_f32(support[(size_t)(d.x & 0xFFFF) * FOUT + lane]);
            int2 rs[4] = {a, b, c, d};
            float vs[4] = {va, vb, vc, vd};
            #pragma unroll
            for (int q = 0; q < 4; ++q) {
                int n = (rs[q].x >> 16) & (NPB - 1);        // wave-uniform
                if (n != curn) {
                    if (curn >= 0 && node0 + curn < N)
                        out[(size_t)(node0 + curn) * FOUT + lane] = accv + bv;
                    curn = n;
                    accv = 0.f;
                }
                accv += vs[q] * __int_as_float(rs[q].y);
            }
            i += 4;
        } else {
            int2 a = sorted[i];
            float va = bf16_to_f32(support[(size_t)(a.x & 0xFFFF) * FOUT + lane]);
            int n = (a.x >> 16) & (NPB - 1);
            if (n != curn) {
                if (curn >= 0 && node0 + curn < N)
                    out[(size_t)(node0 + curn) * FOUT + lane] = accv + bv;
                curn = n;
                accv = 0.f;
            }
            accv += va * __int_as_float(a.y);
            i += 1;
        }
    }
    if (curn >= 0 && node0 + curn < N)
        out[(size_t)(node0 + curn) * FOUT + lane] = accv + bv;

    // zero-count nodes get bias rows
    for (int n = w; n < NPB; n += 4) {
        int node = node0 + n;
        if (node < N && cnt[n] == 0)
            out[(size_t)node * FOUT + lane] = bv;
    }

    // overflow fallback (never triggers at this size; kept for correctness)
    if (nrec > CAP) {
        __threadfence();
        __syncthreads();
        for (int j = base + CAP + tid; j < endB; j += 256) {
            int2 r = tmp[j];
            int node = node0 + ((r.x >> 16) & (NPB - 1));
            float wgt = __int_as_float(r.y);
            for (int f = 0; f < FOUT; ++f) {
                float v = bf16_to_f32(support[(size_t)(r.x & 0xFFFF) * FOUT + f]);
                atomicAdd(&out[(size_t)node * FOUT + f], v * wgt);
            }
        }
    }
}

extern "C" void kernel_launch(void* const* d_in, const int* in_sizes, int n_in,
                              void* d_out, int out_size, void* d_ws, size_t ws_size,
                              hipStream_t stream) {
    const float* x    = (const float*)d_in[0];
    const float* t    = (const float*)d_in[1];
    const int*   src  = (const int*)d_in[2];
    const int*   dst  = (const int*)d_in[3];
    const float* ev   = (const float*)d_in[4];
    const float* W    = (const float*)d_in[5];
    const float* bias = (const float*)d_in[6];
    float* out = (float*)d_out;

    const int N = in_sizes[1];   // 50000
    const int E = in_sizes[2];   // 800000

    char*   ws        = (char*)d_ws;
    ushort* support   = (ushort*)ws;
    int*    hist      = (int*)(ws + OFF_HIST);
    int*    blocksums = (int*)(ws + OFF_BLOCKSUMS);
    int2*   tmp       = (int2*)(ws + OFF_TMP);

    const int GB   = (N + TILE_ROWS - 1) / TILE_ROWS;    // 782 gemm blocks
    const int SB   = (E + EPB - 1) / EPB;                // 196 sort blocks
    const int NBUK = (N + NPB - 1) / NPB;                // 782 coarse buckets
    const int M    = NBUK * SB;                          // 153,272
    const int NBS  = (M + SCAN_CHUNK - 1) / SCAN_CHUNK;  // 150 (<=256)

    // 1) fused: support = bf16((x@W)*t) + coarse histogram
    gemm_hist_kernel<<<GB + SB, 256, 0, stream>>>(
        x, t, W, support, N, dst, hist, E, SB, NBUK, GB);

    // 2) exclusive scan of hist matrix
    scan_sums_kernel<<<NBS, 256, 0, stream>>>(hist, blocksums, M);
    scan_block_kernel<<<1, 256, 0, stream>>>(blocksums, NBS);
    scan_apply_excl_kernel<<<NBS, 256, 0, stream>>>(hist, blocksums, M);

    // 3) coarse scatter into bucket-ordered tmp
    coarse_scatter_kernel<<<SB, 256, 0, stream>>>(
        src, dst, ev, hist, tmp, E, SB, NBUK);

    // 4) per-bucket LDS fine-sort + register-walk accumulate -> out (+bias)
    bucket_gather_kernel<<<NBUK, 256, 0, stream>>>(
        hist, tmp, support, bias, out, E, N, SB, NBUK);
}

// Round 9
// 155.871 us; speedup vs baseline: 3.0085x; 1.0959x over previous
//
#include <hip/hip_runtime.h>
#include <hip/hip_bf16.h>

#define FIN 128
#define FOUT 64
#define TILE_ROWS 64       // rows per gemm block = 4 waves x 16

#define EPB 2048           // edges per sort chunk
#define NPB 32             // nodes per bucket (d >> 5)
#define NBUK_MAX 1600
#define CAP 768            // records cap per bucket (mean 512, +11 sigma)

// Workspace layout (bytes, 16B-aligned):
//   [0, 6,400,000)            support   : N*64 bf16
//   [6,400,000, +16,384)      Wt        : 64x128 bf16  (W transposed)
//   [6,416,384, +2,450,784)   hist      : NBUK*SBP int, bucket-major [j][c]
//   [8,867,168, +1,024)       blocksums : 256 int
//   [8,868,192, +6,400,000)   tmp       : E int2 {src | dloc<<16, ev}
#define OFF_WT        6400000
#define OFF_HIST      6416384
#define OFF_BLOCKSUMS 8867168
#define OFF_TMP       8868192

#define SCAN_CHUNK 4096    // elements per scan block (256 thr x 16)

typedef short bf16x8 __attribute__((ext_vector_type(8)));
typedef float f32x4  __attribute__((ext_vector_type(4)));

// f32 -> bf16 round-to-nearest-even (bit-level)
__device__ inline ushort f32_to_bf16_rne(float f) {
    unsigned u = __float_as_uint(f);
    u += 0x7FFFu + ((u >> 16) & 1u);
    return (ushort)(u >> 16);
}
__device__ inline float bf16_to_f32(ushort h) {
    return __uint_as_float((unsigned)h << 16);
}

// ---------------------------------------------------------------------------
// prep: Wt[n][k] = bf16(W[k][n])  (16 KB, L1-resident for the gemm kernel)
// ---------------------------------------------------------------------------
__global__ __launch_bounds__(256) void prep_wt_kernel(
    const float* __restrict__ W, ushort* __restrict__ Wt)
{
    const int tid = threadIdx.x;
    for (int i = 0; i < 32; ++i) {
        int flat = i * 256 + tid;          // 8192 elements
        int k = flat >> 6;
        int n = flat & 63;
        Wt[n * FIN + k] = f32_to_bf16_rne(W[flat]);
    }
}

// ---------------------------------------------------------------------------
// Fused dispatch.
// blocks [0,GB): MFMA gemm, support(bf16) = (x @ W) * t[:,None].
//   No LDS, no barriers. A-frags direct from global x (f32->bf16 in regs),
//   B-frags direct from global Wt (bf16, L1-hot).
//   Layouts (HW-verified): A[m=lane&15][k=quad*8+j]; B-frag == A pattern on
//   Wt rows; C/D col=lane&15, row=quad*4+reg.
// blocks [GB,..): coarse dst histogram, chunk XCD-swizzled.
// ---------------------------------------------------------------------------
__global__ __launch_bounds__(256) void gemm_hist_kernel(
    const float* __restrict__ x, const float* __restrict__ t,
    const ushort* __restrict__ Wt, ushort* __restrict__ support, int N,
    const int* __restrict__ dst, int* __restrict__ hist,
    int E, int SBP, int NBUK, int G, int GB)
{
    __shared__ int h[NBUK_MAX];
    const int tid = threadIdx.x;

    if (blockIdx.x >= GB) {
        // ---- histogram branch ----
        const int hb    = blockIdx.x - GB;
        const int chunk = (hb & 7) * G + (hb >> 3);   // consecutive chunks -> same XCD
        for (int i = tid; i < NBUK; i += 256) h[i] = 0;
        __syncthreads();
        const int e0 = chunk * EPB;
        for (int i = tid; i < EPB; i += 256) {
            int e = e0 + i;
            if (e < E) atomicAdd(&h[dst[e] >> 5], 1);
        }
        __syncthreads();
        for (int i = tid; i < NBUK; i += 256)
            hist[i * SBP + chunk] = h[i];
        return;
    }

    // ---- MFMA gemm branch ----
    const int lane = tid & 63;
    const int w    = tid >> 6;          // wave 0..3
    const int ln   = lane & 15;
    const int q    = lane >> 4;         // quad 0..3
    const int rowb = blockIdx.x * TILE_ROWS + w * 16;
    const int arow = rowb + ln;         // A-frag row for this lane

    f32x4 acc[4];
    #pragma unroll
    for (int nt = 0; nt < 4; ++nt)
        #pragma unroll
        for (int r = 0; r < 4; ++r) acc[nt][r] = 0.f;

    const bool aok = (arow < N);
    const float* xrow = &x[(size_t)arow * FIN];

    #pragma unroll
    for (int kc = 0; kc < 4; ++kc) {
        float xs[8];
        #pragma unroll
        for (int j = 0; j < 8; ++j) xs[j] = 0.f;
        if (aok) {
            float4 x0 = *(const float4*)&xrow[kc * 32 + q * 8];
            float4 x1 = *(const float4*)&xrow[kc * 32 + q * 8 + 4];
            xs[0] = x0.x; xs[1] = x0.y; xs[2] = x0.z; xs[3] = x0.w;
            xs[4] = x1.x; xs[5] = x1.y; xs[6] = x1.z; xs[7] = x1.w;
        }
        bf16x8 a;
        #pragma unroll
        for (int j = 0; j < 8; ++j) a[j] = (short)f32_to_bf16_rne(xs[j]);

        #pragma unroll
        for (int nt = 0; nt < 4; ++nt) {
            bf16x8 b = *(const bf16x8*)&Wt[(nt * 16 + ln) * FIN + kc * 32 + q * 8];
            acc[nt] = __builtin_amdgcn_mfma_f32_16x16x32_bf16(a, b, acc[nt], 0, 0, 0);
        }
    }

    // epilogue: D[m=q*4+reg][n=ln]; scale by t[row]; store bf16
    #pragma unroll
    for (int reg = 0; reg < 4; ++reg) {
        int r = rowb + q * 4 + reg;
        if (r < N) {
            float tv = t[r];
            #pragma unroll
            for (int nt = 0; nt < 4; ++nt)
                support[(size_t)r * FOUT + nt * 16 + ln] =
                    f32_to_bf16_rne(acc[nt][reg] * tv);
        }
    }
}

// ---------------------------------------------------------------------------
// scan stage 1: per-block sums of SCAN_CHUNK elements
// ---------------------------------------------------------------------------
__global__ __launch_bounds__(256) void scan_sums_kernel(
    const int* __restrict__ counts, int* __restrict__ blocksums, int M)
{
    __shared__ int red[256];
    const int tid  = threadIdx.x;
    const int base = blockIdx.x * SCAN_CHUNK + tid * 16;

    int s = 0;
    #pragma unroll
    for (int v = 0; v < 4; ++v) {
        int idx = base + v * 4;
        if (idx + 3 < M) {
            int4 c = *(const int4*)&counts[idx];
            s += c.x + c.y + c.z + c.w;
        } else {
            for (int i = 0; i < 4; ++i)
                if (idx + i < M) s += counts[idx + i];
        }
    }
    red[tid] = s;
    __syncthreads();
    #pragma unroll
    for (int d = 128; d > 0; d >>= 1) {
        if (tid < d) red[tid] += red[tid + d];
        __syncthreads();
    }
    if (tid == 0) blocksums[blockIdx.x] = red[0];
}

// ---------------------------------------------------------------------------
// scan stage 2: one block scans <=256 block sums -> exclusive
// ---------------------------------------------------------------------------
__global__ __launch_bounds__(256) void scan_block_kernel(
    int* __restrict__ blocksums, int NB)
{
    __shared__ int s[256];
    const int tid = threadIdx.x;
    int v = (tid < NB) ? blocksums[tid] : 0;
    s[tid] = v;
    __syncthreads();
    #pragma unroll
    for (int d = 1; d < 256; d <<= 1) {
        int add = (tid >= d) ? s[tid - d] : 0;
        __syncthreads();
        s[tid] += add;
        __syncthreads();
    }
    if (tid < NB) blocksums[tid] = s[tid] - v;
}

// ---------------------------------------------------------------------------
// scan stage 3: counts[j] <- exclusive prefix, in place
// ---------------------------------------------------------------------------
__global__ __launch_bounds__(256) void scan_apply_excl_kernel(
    int* __restrict__ counts, const int* __restrict__ blocksums, int M)
{
    __shared__ int s[256];
    const int tid  = threadIdx.x;
    const int base = blockIdx.x * SCAN_CHUNK + tid * 16;

    int c[16];
    int mysum = 0;
    #pragma unroll
    for (int v = 0; v < 4; ++v) {
        int idx = base + v * 4;
        int4 cc = make_int4(0, 0, 0, 0);
        if (idx + 3 < M) {
            cc = *(const int4*)&counts[idx];
        } else {
            if (idx + 0 < M) cc.x = counts[idx + 0];
            if (idx + 1 < M) cc.y = counts[idx + 1];
            if (idx + 2 < M) cc.z = counts[idx + 2];
            if (idx + 3 < M) cc.w = counts[idx + 3];
        }
        c[v * 4 + 0] = cc.x; c[v * 4 + 1] = cc.y;
        c[v * 4 + 2] = cc.z; c[v * 4 + 3] = cc.w;
        mysum += cc.x + cc.y + cc.z + cc.w;
    }
    s[tid] = mysum;
    __syncthreads();
    #pragma unroll
    for (int d = 1; d < 256; d <<= 1) {
        int add = (tid >= d) ? s[tid - d] : 0;
        __syncthreads();
        s[tid] += add;
        __syncthreads();
    }
    int ex = blocksums[blockIdx.x] + s[tid] - mysum;
    #pragma unroll
    for (int i = 0; i < 16; ++i) {
        if (base + i < M) {
            counts[base + i] = ex;
            ex += c[i];
        }
    }
}

// ---------------------------------------------------------------------------
// coarse scatter: private per-(chunk,bucket) cursors (LDS int atomics only),
// chunk XCD-swizzled so adjacent chunks' runs dirty lines in ONE L2.
// rec = {src | (d&31)<<16, ev_bits}   (src < 65536: N = 50000 ok)
// ---------------------------------------------------------------------------
__global__ __launch_bounds__(256) void coarse_scatter_kernel(
    const int* __restrict__ src, const int* __restrict__ dst,
    const float* __restrict__ ev, const int* __restrict__ scanned,
    int2* __restrict__ tmp, int E, int SBP, int NBUK, int G)
{
    __shared__ int cur[NBUK_MAX];
    const int tid   = threadIdx.x;
    const int b     = blockIdx.x;
    const int chunk = (b & 7) * G + (b >> 3);
    for (int i = tid; i < NBUK; i += 256)
        cur[i] = scanned[i * SBP + chunk];
    __syncthreads();

    const int e0 = chunk * EPB;
    for (int i = tid; i < EPB; i += 256) {
        int e = e0 + i;
        if (e < E) {
            int d   = dst[e];
            int pos = atomicAdd(&cur[d >> 5], 1);
            tmp[pos] = make_int2(src[e] | ((d & (NPB - 1)) << 16),
                                 __float_as_int(ev[e]));
        }
    }
}

// ---------------------------------------------------------------------------
// bucket_gather: one block per 32-node bucket (grid ~1563 = 6/CU). tmp read
// ONCE into LDS raw[]; count+scan+reorder in LDS (int atomics); each wave
// walks its contiguous 8-node record range with a register accumulator and
// wave-uniform node-boundary flush. No float atomics.
// ---------------------------------------------------------------------------
__global__ __launch_bounds__(256) void bucket_gather_kernel(
    const int* __restrict__ scanned, const int2* __restrict__ tmp,
    const ushort* __restrict__ support, const float* __restrict__ bias,
    float* __restrict__ out, int E, int N, int SBP, int NBUK)
{
    __shared__ int2 raw[CAP];           // 6 KB
    __shared__ int2 sorted[CAP];        // 6 KB
    __shared__ int  cnt[NPB];
    __shared__ int  incl[NPB];
    __shared__ int  starts[NPB + 1];
    __shared__ int  cur[NPB];

    const int tid   = threadIdx.x;
    const int w     = tid >> 6;
    const int lane  = tid & 63;
    const int B     = blockIdx.x;
    const int node0 = B * NPB;

    const int base   = scanned[B * SBP];
    const int endB   = (B + 1 < NBUK) ? scanned[(B + 1) * SBP] : E;
    const int nrec   = endB - base;
    const int placed = (nrec < CAP) ? nrec : CAP;

    if (tid < NPB) cnt[tid] = 0;
    __syncthreads();

    // single global read of tmp: stage + count
    for (int i = tid; i < placed; i += 256) {
        int2 r = tmp[base + i];
        raw[i] = r;
        atomicAdd(&cnt[(r.x >> 16) & (NPB - 1)], 1);
    }
    __syncthreads();

    // inclusive Hillis-Steele over 32 counters
    if (tid < NPB) incl[tid] = cnt[tid];
    __syncthreads();
    #pragma unroll
    for (int d = 1; d < NPB; d <<= 1) {
        int v = (tid < NPB && tid >= d) ? incl[tid - d] : 0;
        __syncthreads();
        if (tid < NPB) incl[tid] += v;
        __syncthreads();
    }
    if (tid < NPB) {
        int st = incl[tid] - cnt[tid];
        starts[tid] = st;
        cur[tid]    = st;
    }
    if (tid == 0) starts[NPB] = placed;
    __syncthreads();

    // reorder LDS -> LDS
    for (int i = tid; i < placed; i += 256) {
        int2 r  = raw[i];
        int pos = atomicAdd(&cur[(r.x >> 16) & (NPB - 1)], 1);
        sorted[pos] = r;
    }
    __syncthreads();

    // walk: wave w owns nodes [w*8, (w+1)*8) == records [rbeg, rend)
    const float bv = bias[lane];
    const int rbeg = starts[w * 8];
    const int rend = starts[w * 8 + 8];

    float accv = 0.f;
    int   curn = -1;

    int i = rbeg;
    while (i < rend) {
        if (i + 4 <= rend) {
            int2 a = sorted[i], b = sorted[i + 1], c = sorted[i + 2], d = sorted[i + 3];
            float va = bf16_to_f32(support[(size_t)(a.x & 0xFFFF) * FOUT + lane]);
            float vb = bf16_to_f32(support[(size_t)(b.x & 0xFFFF) * FOUT + lane]);
            float vc = bf16_to_f32(support[(size_t)(c.x & 0xFFFF) * FOUT + lane]);
            float vd = bf16_to_f32(support[(size_t)(d.x & 0xFFFF) * FOUT + lane]);
            int2 rs[4] = {a, b, c, d};
            float vs[4] = {va, vb, vc, vd};
            #pragma unroll
            for (int qq = 0; qq < 4; ++qq) {
                int n = (rs[qq].x >> 16) & (NPB - 1);       // wave-uniform
                if (n != curn) {
                    if (curn >= 0 && node0 + curn < N)
                        out[(size_t)(node0 + curn) * FOUT + lane] = accv + bv;
                    curn = n;
                    accv = 0.f;
                }
                accv += vs[qq] * __int_as_float(rs[qq].y);
            }
            i += 4;
        } else {
            int2 a = sorted[i];
            float va = bf16_to_f32(support[(size_t)(a.x & 0xFFFF) * FOUT + lane]);
            int n = (a.x >> 16) & (NPB - 1);
            if (n != curn) {
                if (curn >= 0 && node0 + curn < N)
                    out[(size_t)(node0 + curn) * FOUT + lane] = accv + bv;
                curn = n;
                accv = 0.f;
            }
            accv += va * __int_as_float(a.y);
            i += 1;
        }
    }
    if (curn >= 0 && node0 + curn < N)
        out[(size_t)(node0 + curn) * FOUT + lane] = accv + bv;

    // zero-count nodes get bias rows
    for (int n = w; n < NPB; n += 4) {
        int node = node0 + n;
        if (node < N && cnt[n] == 0)
            out[(size_t)node * FOUT + lane] = bv;
    }

    // overflow fallback (never triggers at this size; kept for correctness)
    if (nrec > CAP) {
        __threadfence();
        __syncthreads();
        for (int j = base + CAP + tid; j < endB; j += 256) {
            int2 r = tmp[j];
            int node = node0 + ((r.x >> 16) & (NPB - 1));
            float wgt = __int_as_float(r.y);
            for (int f = 0; f < FOUT; ++f) {
                float v = bf16_to_f32(support[(size_t)(r.x & 0xFFFF) * FOUT + f]);
                atomicAdd(&out[(size_t)node * FOUT + f], v * wgt);
            }
        }
    }
}

extern "C" void kernel_launch(void* const* d_in, const int* in_sizes, int n_in,
                              void* d_out, int out_size, void* d_ws, size_t ws_size,
                              hipStream_t stream) {
    const float* x    = (const float*)d_in[0];
    const float* t    = (const float*)d_in[1];
    const int*   src  = (const int*)d_in[2];
    const int*   dst  = (const int*)d_in[3];
    const float* ev   = (const float*)d_in[4];
    const float* W    = (const float*)d_in[5];
    const float* bias = (const float*)d_in[6];
    float* out = (float*)d_out;

    const int N = in_sizes[1];   // 50000
    const int E = in_sizes[2];   // 800000

    char*   ws        = (char*)d_ws;
    ushort* support   = (ushort*)ws;
    ushort* Wt        = (ushort*)(ws + OFF_WT);
    int*    hist      = (int*)(ws + OFF_HIST);
    int*    blocksums = (int*)(ws + OFF_BLOCKSUMS);
    int2*   tmp       = (int2*)(ws + OFF_TMP);

    const int GB   = (N + TILE_ROWS - 1) / TILE_ROWS;       // 782
    const int SBr  = (E + EPB - 1) / EPB;                   // 391 real chunks
    const int SBP  = ((SBr + 7) / 8) * 8;                   // 392 (8-divisible)
    const int G    = SBP / 8;                               // 49
    const int NBUK = (N + NPB - 1) / NPB;                   // 1563
    const int M    = NBUK * SBP;                            // 612,696
    const int NBS  = (M + SCAN_CHUNK - 1) / SCAN_CHUNK;     // 150 (<=256)

    // 0) Wt = bf16(W^T)
    prep_wt_kernel<<<1, 256, 0, stream>>>(W, Wt);

    // 1) fused: MFMA gemm (support) + coarse histogram
    gemm_hist_kernel<<<GB + SBP, 256, 0, stream>>>(
        x, t, Wt, support, N, dst, hist, E, SBP, NBUK, G, GB);

    // 2) exclusive scan of hist matrix
    scan_sums_kernel<<<NBS, 256, 0, stream>>>(hist, blocksums, M);
    scan_block_kernel<<<1, 256, 0, stream>>>(blocksums, NBS);
    scan_apply_excl_kernel<<<NBS, 256, 0, stream>>>(hist, blocksums, M);

    // 3) coarse scatter into bucket-ordered tmp (XCD-grouped writes)
    coarse_scatter_kernel<<<SBP, 256, 0, stream>>>(
        src, dst, ev, hist, tmp, E, SBP, NBUK, G);

    // 4) per-bucket LDS sort + register-walk accumulate -> out (+bias)
    bucket_gather_kernel<<<NBUK, 256, 0, stream>>>(
        hist, tmp, support, bias, out, E, N, SBP, NBUK);
}

// Round 10
// 149.601 us; speedup vs baseline: 3.1347x; 1.0419x over previous
//
#include <hip/hip_runtime.h>
#include <hip/hip_bf16.h>

#define FIN 128
#define FOUT 64
#define TILE_ROWS 64       // rows per gemm block = 4 waves x 16

#define EPB 2048           // edges per sort chunk
#define NPB 32             // nodes per bucket (d >> 5)
#define NBUK_MAX 1600
#define CAP 768            // records cap per bucket (mean 512, +11 sigma)

// Workspace layout (bytes, 16B-aligned):
//   [0, 6,400,000)            support   : N*64 bf16
//   [6,400,000, +2,450,784)   hist      : NBUK*SBP int, bucket-major [j][c]
//   [8,860,000, +1,024)       blocksums : 256 int
//   [8,861,024, +6,400,000)   tmp       : E int2 {src | dloc<<16, ev}
#define OFF_HIST      6400000
#define OFF_BLOCKSUMS 8860000
#define OFF_TMP       8861024

#define SCAN_CHUNK 4096    // elements per scan block (256 thr x 16)

typedef short bf16x8 __attribute__((ext_vector_type(8)));
typedef float f32x4  __attribute__((ext_vector_type(4)));

// f32 -> bf16 round-to-nearest-even (bit-level)
__device__ inline ushort f32_to_bf16_rne(float f) {
    unsigned u = __float_as_uint(f);
    u += 0x7FFFu + ((u >> 16) & 1u);
    return (ushort)(u >> 16);
}
__device__ inline float bf16_to_f32(ushort h) {
    return __uint_as_float((unsigned)h << 16);
}

// ---------------------------------------------------------------------------
// Fused dispatch.
// blocks [0,GB): MFMA gemm, support(bf16) = (x @ W) * t[:,None].
//   B-frags converted from the f32 W in-registers (L1-hot scalar loads; the
//   (ln,q) lane partition reads W exactly once per wave) -- no prep kernel,
//   no LDS, no barriers in this branch.
//   Layouts (HW-verified): A[m=lane&15][k=quad*8+j]; B-frag same pattern on
//   W^T rows; C/D col=lane&15, row=quad*4+reg.
// blocks [GB,..): coarse dst histogram, chunk XCD-swizzled.
// ---------------------------------------------------------------------------
__global__ __launch_bounds__(256) void gemm_hist_kernel(
    const float* __restrict__ x, const float* __restrict__ t,
    const float* __restrict__ W, ushort* __restrict__ support, int N,
    const int* __restrict__ dst, int* __restrict__ hist,
    int E, int SBP, int NBUK, int G, int GB)
{
    __shared__ int h[NBUK_MAX];
    const int tid = threadIdx.x;

    if (blockIdx.x >= GB) {
        // ---- histogram branch ----
        const int hb    = blockIdx.x - GB;
        const int chunk = (hb & 7) * G + (hb >> 3);   // adjacent chunks -> same XCD
        for (int i = tid; i < NBUK; i += 256) h[i] = 0;
        __syncthreads();
        const int e0 = chunk * EPB;
        for (int i = tid; i < EPB; i += 256) {
            int e = e0 + i;
            if (e < E) atomicAdd(&h[dst[e] >> 5], 1);
        }
        __syncthreads();
        for (int i = tid; i < NBUK; i += 256)
            hist[i * SBP + chunk] = h[i];
        return;
    }

    // ---- MFMA gemm branch ----
    const int lane = tid & 63;
    const int w    = tid >> 6;          // wave 0..3
    const int ln   = lane & 15;
    const int q    = lane >> 4;         // quad 0..3
    const int rowb = blockIdx.x * TILE_ROWS + w * 16;
    const int arow = rowb + ln;

    // B-frags: bfr[kc][nt][j] = bf16(W[kc*32+q*8+j][nt*16+ln])
    bf16x8 bfr[4][4];
    #pragma unroll
    for (int kc = 0; kc < 4; ++kc)
        #pragma unroll
        for (int nt = 0; nt < 4; ++nt)
            #pragma unroll
            for (int j = 0; j < 8; ++j)
                bfr[kc][nt][j] = (short)f32_to_bf16_rne(
                    W[(kc * 32 + q * 8 + j) * FOUT + nt * 16 + ln]);

    f32x4 acc[4];
    #pragma unroll
    for (int nt = 0; nt < 4; ++nt)
        #pragma unroll
        for (int r = 0; r < 4; ++r) acc[nt][r] = 0.f;

    const bool aok = (arow < N);
    const float* xrow = &x[(size_t)arow * FIN];

    #pragma unroll
    for (int kc = 0; kc < 4; ++kc) {
        float xs[8];
        #pragma unroll
        for (int j = 0; j < 8; ++j) xs[j] = 0.f;
        if (aok) {
            float4 x0 = *(const float4*)&xrow[kc * 32 + q * 8];
            float4 x1 = *(const float4*)&xrow[kc * 32 + q * 8 + 4];
            xs[0] = x0.x; xs[1] = x0.y; xs[2] = x0.z; xs[3] = x0.w;
            xs[4] = x1.x; xs[5] = x1.y; xs[6] = x1.z; xs[7] = x1.w;
        }
        bf16x8 a;
        #pragma unroll
        for (int j = 0; j < 8; ++j) a[j] = (short)f32_to_bf16_rne(xs[j]);

        #pragma unroll
        for (int nt = 0; nt < 4; ++nt)
            acc[nt] = __builtin_amdgcn_mfma_f32_16x16x32_bf16(a, bfr[kc][nt],
                                                              acc[nt], 0, 0, 0);
    }

    // epilogue: D[m=q*4+reg][n=ln]; scale by t[row]; store bf16
    #pragma unroll
    for (int reg = 0; reg < 4; ++reg) {
        int r = rowb + q * 4 + reg;
        if (r < N) {
            float tv = t[r];
            #pragma unroll
            for (int nt = 0; nt < 4; ++nt)
                support[(size_t)r * FOUT + nt * 16 + ln] =
                    f32_to_bf16_rne(acc[nt][reg] * tv);
        }
    }
}

// ---------------------------------------------------------------------------
// scan stage 1: per-block sums of SCAN_CHUNK elements
// ---------------------------------------------------------------------------
__global__ __launch_bounds__(256) void scan_sums_kernel(
    const int* __restrict__ counts, int* __restrict__ blocksums, int M)
{
    __shared__ int red[256];
    const int tid  = threadIdx.x;
    const int base = blockIdx.x * SCAN_CHUNK + tid * 16;

    int s = 0;
    #pragma unroll
    for (int v = 0; v < 4; ++v) {
        int idx = base + v * 4;
        if (idx + 3 < M) {
            int4 c = *(const int4*)&counts[idx];
            s += c.x + c.y + c.z + c.w;
        } else {
            for (int i = 0; i < 4; ++i)
                if (idx + i < M) s += counts[idx + i];
        }
    }
    red[tid] = s;
    __syncthreads();
    #pragma unroll
    for (int d = 128; d > 0; d >>= 1) {
        if (tid < d) red[tid] += red[tid + d];
        __syncthreads();
    }
    if (tid == 0) blocksums[blockIdx.x] = red[0];
}

// ---------------------------------------------------------------------------
// scan stage 2 (fused top-scan): wave 0 of every block shfl-scans the <=256
// blocksums to find its own exclusive offset, then counts[j] <- excl prefix.
// ---------------------------------------------------------------------------
__global__ __launch_bounds__(256) void scan_apply_kernel(
    int* __restrict__ counts, const int* __restrict__ blocksums, int M, int NB)
{
    __shared__ int s[256];
    __shared__ int bex;
    const int tid  = threadIdx.x;
    const int base = blockIdx.x * SCAN_CHUNK + tid * 16;

    // inline exclusive scan of blocksums (wave 0, windows of 64, no barriers)
    if (tid < 64) {
        int carry = 0;
        for (int w0 = 0; w0 < NB; w0 += 64) {
            int idx = w0 + tid;
            int v   = (idx < NB) ? blocksums[idx] : 0;
            int val = v;
            #pragma unroll
            for (int d = 1; d < 64; d <<= 1) {
                int n = __shfl_up(val, d);
                if (tid >= d) val += n;
            }
            if (idx == (int)blockIdx.x) bex = carry + val - v;
            carry += __shfl(val, 63);
        }
    }

    int c[16];
    int mysum = 0;
    #pragma unroll
    for (int v = 0; v < 4; ++v) {
        int idx = base + v * 4;
        int4 cc = make_int4(0, 0, 0, 0);
        if (idx + 3 < M) {
            cc = *(const int4*)&counts[idx];
        } else {
            if (idx + 0 < M) cc.x = counts[idx + 0];
            if (idx + 1 < M) cc.y = counts[idx + 1];
            if (idx + 2 < M) cc.z = counts[idx + 2];
            if (idx + 3 < M) cc.w = counts[idx + 3];
        }
        c[v * 4 + 0] = cc.x; c[v * 4 + 1] = cc.y;
        c[v * 4 + 2] = cc.z; c[v * 4 + 3] = cc.w;
        mysum += cc.x + cc.y + cc.z + cc.w;
    }
    s[tid] = mysum;
    __syncthreads();
    #pragma unroll
    for (int d = 1; d < 256; d <<= 1) {
        int add = (tid >= d) ? s[tid - d] : 0;
        __syncthreads();
        s[tid] += add;
        __syncthreads();
    }
    int ex = bex + s[tid] - mysum;
    #pragma unroll
    for (int i = 0; i < 16; ++i) {
        if (base + i < M) {
            counts[base + i] = ex;
            ex += c[i];
        }
    }
}

// ---------------------------------------------------------------------------
// coarse scatter: private per-(chunk,bucket) cursors (LDS int atomics only),
// chunk XCD-swizzled so adjacent chunks' runs dirty lines in ONE L2.
// rec = {src | (d&31)<<16, ev_bits}   (src < 65536: N = 50000 ok)
// ---------------------------------------------------------------------------
__global__ __launch_bounds__(256) void coarse_scatter_kernel(
    const int* __restrict__ src, const int* __restrict__ dst,
    const float* __restrict__ ev, const int* __restrict__ scanned,
    int2* __restrict__ tmp, int E, int SBP, int NBUK, int G)
{
    __shared__ int cur[NBUK_MAX];
    const int tid   = threadIdx.x;
    const int b     = blockIdx.x;
    const int chunk = (b & 7) * G + (b >> 3);
    for (int i = tid; i < NBUK; i += 256)
        cur[i] = scanned[i * SBP + chunk];
    __syncthreads();

    const int e0 = chunk * EPB;
    for (int i = tid; i < EPB; i += 256) {
        int e = e0 + i;
        if (e < E) {
            int d   = dst[e];
            int pos = atomicAdd(&cur[d >> 5], 1);
            tmp[pos] = make_int2(src[e] | ((d & (NPB - 1)) << 16),
                                 __float_as_int(ev[e]));
        }
    }
}

// ---------------------------------------------------------------------------
// bucket_gather: one block per 32-node bucket. tmp read once into LDS;
// count (int atomics) -> wave-0 shfl scan -> reorder -> register-walk with
// wave-uniform node-boundary flush. 4 barriers total, no float atomics.
// ---------------------------------------------------------------------------
__global__ __launch_bounds__(256) void bucket_gather_kernel(
    const int* __restrict__ scanned, const int2* __restrict__ tmp,
    const ushort* __restrict__ support, const float* __restrict__ bias,
    float* __restrict__ out, int E, int N, int SBP, int NBUK)
{
    __shared__ int2 raw[CAP];           // 6 KB
    __shared__ int2 sorted[CAP];        // 6 KB
    __shared__ int  cnt[NPB];
    __shared__ int  starts[NPB + 1];
    __shared__ int  cur[NPB];

    const int tid   = threadIdx.x;
    const int w     = tid >> 6;
    const int lane  = tid & 63;
    const int B     = blockIdx.x;
    const int node0 = B * NPB;

    const int base   = scanned[B * SBP];
    const int endB   = (B + 1 < NBUK) ? scanned[(B + 1) * SBP] : E;
    const int nrec   = endB - base;
    const int placed = (nrec < CAP) ? nrec : CAP;

    if (tid < NPB) cnt[tid] = 0;
    __syncthreads();

    // single global read of tmp: stage + count
    for (int i = tid; i < placed; i += 256) {
        int2 r = tmp[base + i];
        raw[i] = r;
        atomicAdd(&cnt[(r.x >> 16) & (NPB - 1)], 1);
    }
    __syncthreads();

    // wave-0 shfl scan over 32 counters (no barriers inside)
    if (tid < 64) {
        int v   = (tid < NPB) ? cnt[tid] : 0;
        int val = v;
        #pragma unroll
        for (int d = 1; d < NPB; d <<= 1) {
            int n = __shfl_up(val, d);
            if (tid >= d) val += n;
        }
        if (tid < NPB) {
            starts[tid] = val - v;
            cur[tid]    = val - v;
        }
        if (tid == 0) starts[NPB] = placed;
    }
    __syncthreads();

    // reorder LDS -> LDS
    for (int i = tid; i < placed; i += 256) {
        int2 r  = raw[i];
        int pos = atomicAdd(&cur[(r.x >> 16) & (NPB - 1)], 1);
        sorted[pos] = r;
    }
    __syncthreads();

    // walk: wave w owns nodes [w*8, (w+1)*8) == records [rbeg, rend)
    const float bv = bias[lane];
    const int rbeg = starts[w * 8];
    const int rend = starts[w * 8 + 8];

    float accv = 0.f;
    int   curn = -1;

    int i = rbeg;
    while (i < rend) {
        if (i + 4 <= rend) {
            int2 a = sorted[i], b = sorted[i + 1], c = sorted[i + 2], d = sorted[i + 3];
            float va = bf16_to_f32(support[(size_t)(a.x & 0xFFFF) * FOUT + lane]);
            float vb = bf16_to_f32(support[(size_t)(b.x & 0xFFFF) * FOUT + lane]);
            float vc = bf16_to_f32(support[(size_t)(c.x & 0xFFFF) * FOUT + lane]);
            float vd = bf16_to_f32(support[(size_t)(d.x & 0xFFFF) * FOUT + lane]);
            int2 rs[4] = {a, b, c, d};
            float vs[4] = {va, vb, vc, vd};
            #pragma unroll
            for (int qq = 0; qq < 4; ++qq) {
                int n = (rs[qq].x >> 16) & (NPB - 1);       // wave-uniform
                if (n != curn) {
                    if (curn >= 0 && node0 + curn < N)
                        out[(size_t)(node0 + curn) * FOUT + lane] = accv + bv;
                    curn = n;
                    accv = 0.f;
                }
                accv += vs[qq] * __int_as_float(rs[qq].y);
            }
            i += 4;
        } else {
            int2 a = sorted[i];
            float va = bf16_to_f32(support[(size_t)(a.x & 0xFFFF) * FOUT + lane]);
            int n = (a.x >> 16) & (NPB - 1);
            if (n != curn) {
                if (curn >= 0 && node0 + curn < N)
                    out[(size_t)(node0 + curn) * FOUT + lane] = accv + bv;
                curn = n;
                accv = 0.f;
            }
            accv += va * __int_as_float(a.y);
            i += 1;
        }
    }
    if (curn >= 0 && node0 + curn < N)
        out[(size_t)(node0 + curn) * FOUT + lane] = accv + bv;

    // zero-count nodes get bias rows
    for (int n = w; n < NPB; n += 4) {
        int node = node0 + n;
        if (node < N && cnt[n] == 0)
            out[(size_t)node * FOUT + lane] = bv;
    }

    // overflow fallback (never triggers at this size; kept for correctness)
    if (nrec > CAP) {
        __threadfence();
        __syncthreads();
        for (int j = base + CAP + tid; j < endB; j += 256) {
            int2 r = tmp[j];
            int node = node0 + ((r.x >> 16) & (NPB - 1));
            float wgt = __int_as_float(r.y);
            for (int f = 0; f < FOUT; ++f) {
                float v = bf16_to_f32(support[(size_t)(r.x & 0xFFFF) * FOUT + f]);
                atomicAdd(&out[(size_t)node * FOUT + f], v * wgt);
            }
        }
    }
}

extern "C" void kernel_launch(void* const* d_in, const int* in_sizes, int n_in,
                              void* d_out, int out_size, void* d_ws, size_t ws_size,
                              hipStream_t stream) {
    const float* x    = (const float*)d_in[0];
    const float* t    = (const float*)d_in[1];
    const int*   src  = (const int*)d_in[2];
    const int*   dst  = (const int*)d_in[3];
    const float* ev   = (const float*)d_in[4];
    const float* W    = (const float*)d_in[5];
    const float* bias = (const float*)d_in[6];
    float* out = (float*)d_out;

    const int N = in_sizes[1];   // 50000
    const int E = in_sizes[2];   // 800000

    char*   ws        = (char*)d_ws;
    ushort* support   = (ushort*)ws;
    int*    hist      = (int*)(ws + OFF_HIST);
    int*    blocksums = (int*)(ws + OFF_BLOCKSUMS);
    int2*   tmp       = (int2*)(ws + OFF_TMP);

    const int GB   = (N + TILE_ROWS - 1) / TILE_ROWS;       // 782
    const int SBr  = (E + EPB - 1) / EPB;                   // 391 real chunks
    const int SBP  = ((SBr + 7) / 8) * 8;                   // 392 (8-divisible)
    const int G    = SBP / 8;                               // 49
    const int NBUK = (N + NPB - 1) / NPB;                   // 1563
    const int M    = NBUK * SBP;                            // 612,696
    const int NBS  = (M + SCAN_CHUNK - 1) / SCAN_CHUNK;     // 150 (<=256)

    // 1) fused: MFMA gemm (inline W->bf16) + coarse histogram
    gemm_hist_kernel<<<GB + SBP, 256, 0, stream>>>(
        x, t, W, support, N, dst, hist, E, SBP, NBUK, G, GB);

    // 2) scan: per-block sums, then apply (top-level scan inlined)
    scan_sums_kernel<<<NBS, 256, 0, stream>>>(hist, blocksums, M);
    scan_apply_kernel<<<NBS, 256, 0, stream>>>(hist, blocksums, M, NBS);

    // 3) coarse scatter into bucket-ordered tmp (XCD-grouped writes)
    coarse_scatter_kernel<<<SBP, 256, 0, stream>>>(
        src, dst, ev, hist, tmp, E, SBP, NBUK, G);

    // 4) per-bucket LDS sort + register-walk accumulate -> out (+bias)
    bucket_gather_kernel<<<NBUK, 256, 0, stream>>>(
        hist, tmp, support, bias, out, E, N, SBP, NBUK);
}